// Round 7
// baseline (326.408 us; speedup 1.0000x reference)
//
#include <hip/hip_runtime.h>
#include <hip/hip_bf16.h>
#include <math.h>

#define NB 16
#define SEQ 512
#define DIM 512
#define NH 8
#define DHEAD 64
#define MROWS (NB*SEQ)   // 8192

typedef __bf16 bf16x8 __attribute__((ext_vector_type(8)));
typedef float  f32x4  __attribute__((ext_vector_type(4)));

typedef __attribute__((address_space(1))) const unsigned int gu32c;
typedef __attribute__((address_space(3))) unsigned int lu32;

__device__ __forceinline__ void gload_lds16(const void* g, void* l) {
    __builtin_amdgcn_global_load_lds((gu32c*)g, (lu32*)l, 16, 0, 0);
}

// ---------------------------------------------------------------------------
// Kernel 1: fused LayerNorm + bf16 cast. One block per (row, which).
// ---------------------------------------------------------------------------
__global__ __launch_bounds__(128)
void ln_fused_kernel(const float* __restrict__ q, const float* __restrict__ k,
                     const float* __restrict__ v,
                     const float* __restrict__ g0, const float* __restrict__ b0,
                     const float* __restrict__ g1, const float* __restrict__ b1,
                     const float* __restrict__ g2, const float* __restrict__ b2,
                     __hip_bfloat16* __restrict__ qn, __hip_bfloat16* __restrict__ kn,
                     __hip_bfloat16* __restrict__ vn) {
    const int row = blockIdx.x, which = blockIdx.y;
    const float* src = which==0 ? q : (which==1 ? k : v);
    const float* gp  = which==0 ? g0 : (which==1 ? g1 : g2);
    const float* bp  = which==0 ? b0 : (which==1 ? b1 : b2);
    __hip_bfloat16* dst = which==0 ? qn : (which==1 ? kn : vn);
    const int t = threadIdx.x;
    float4 a = *(const float4*)(src + (size_t)row*DIM + t*4);
    float s  = a.x + a.y + a.z + a.w;
    float ss = a.x*a.x + a.y*a.y + a.z*a.z + a.w*a.w;
    #pragma unroll
    for (int off = 32; off > 0; off >>= 1) {
        s  += __shfl_down(s,  off);
        ss += __shfl_down(ss, off);
    }
    __shared__ float red[4];
    if ((t & 63) == 0) { red[(t>>6)*2 + 0] = s; red[(t>>6)*2 + 1] = ss; }
    __syncthreads();
    const float S = red[0] + red[2], SS = red[1] + red[3];
    const float mean = S * (1.0f/DIM);
    const float rstd = rsqrtf(SS * (1.0f/DIM) - mean*mean + 1e-5f);
    const float4 gv = *(const float4*)(gp + t*4);
    const float4 bv = *(const float4*)(bp + t*4);
    union { ushort4 u; __hip_bfloat16 h[4]; } o;
    o.h[0] = __float2bfloat16((a.x-mean)*rstd*gv.x + bv.x);
    o.h[1] = __float2bfloat16((a.y-mean)*rstd*gv.y + bv.y);
    o.h[2] = __float2bfloat16((a.z-mean)*rstd*gv.z + bv.z);
    o.h[3] = __float2bfloat16((a.w-mean)*rstd*gv.w + bv.w);
    *(ushort4*)(dst + (size_t)row*DIM + t*4) = o.u;
}

// ---------------------------------------------------------------------------
// Kernel 2: fp32 -> bf16 cast of the 5 weight matrices (each 512x512).
// ---------------------------------------------------------------------------
__global__ __launch_bounds__(256)
void wconv_kernel(const float* __restrict__ w0, const float* __restrict__ w1,
                  const float* __restrict__ w2, const float* __restrict__ w3,
                  const float* __restrict__ w4, __hip_bfloat16* __restrict__ out) {
    const int m = blockIdx.y;
    const float* src = (m==0)?w0:(m==1)?w1:(m==2)?w2:(m==3)?w3:w4;
    __hip_bfloat16* dst = out + (size_t)m*DIM*DIM;
    const int i = (blockIdx.x*256 + threadIdx.x)*4;
    float4 x = *(const float4*)(src + i);
    union { ushort4 u; __hip_bfloat16 h[4]; } r;
    r.h[0]=__float2bfloat16(x.x); r.h[1]=__float2bfloat16(x.y);
    r.h[2]=__float2bfloat16(x.z); r.h[3]=__float2bfloat16(x.w);
    *(ushort4*)(dst + i) = r.u;
}

// ---------------------------------------------------------------------------
// MFMA GEMM inner loop, v3: counted-vmcnt depth-2 pipeline.
//  - 2 LDS buffers, staged 2 K-tiles ahead; per step s_waitcnt vmcnt(4)
//    (next tile's 4 loads REMAIN in flight across the barrier), raw
//    s_barrier, ds_read + lgkmcnt(0) + sched_barrier (rule #18), 16 MFMA,
//    s_barrier, STAGE(kt+2) into the consumed buffer. vmcnt(0) only at the
//    peeled final tile.
//  - LDS swizzle (both-sides, rule #21): global chunk gslot ^= (row>>1)&3,
//    linear LDS dest; read byte = row*64 + ((lg ^ ((lr>>1)&3))<<4).
//    Breaks the 8-way bank conflict of 64B-stride rows down to 2-way (free);
//    coalescing unchanged (permutation stays within each row's 64B window).
// ---------------------------------------------------------------------------
__device__ __forceinline__ void gemm_core(const __hip_bfloat16* __restrict__ A,
                                          const __hip_bfloat16* __restrict__ W,
                                          __hip_bfloat16 (&Al)[2][128*32],
                                          __hip_bfloat16 (&Bl)[2][128*32],
                                          int tid, int bm, int bn,
                                          f32x4 (&acc)[4][4]) {
    const int l = tid&63, lr = l&15, lg = l>>4;
    const int w = tid>>6, wr = w>>1, wc = w&1;
    const int row0  = tid >> 2;                       // staging row (issue 0)
    const int gslot = (tid&3) ^ ((row0>>1)&3);        // swizzled 16B slot
    const __hip_bfloat16* Ag = A + (size_t)(bm*128 + row0)*DIM + gslot*8;
    const __hip_bfloat16* Wg = W + (size_t)(bn*128 + row0)*DIM + gslot*8;
    // read-side swizzle slot (constant per lane; (row>>1)&3 == (lr>>1)&3)
    const int tsw = (lg ^ ((lr>>1)&3)) << 4;

    auto STAGE = [&](int kt, int buf) {
        gload_lds16(Ag + kt*32,           (char*)Al[buf] + tid*16);
        gload_lds16(Ag + kt*32 + 64*DIM,  (char*)Al[buf] + 4096 + tid*16);
        gload_lds16(Wg + kt*32,           (char*)Bl[buf] + tid*16);
        gload_lds16(Wg + kt*32 + 64*DIM,  (char*)Bl[buf] + 4096 + tid*16);
    };
    auto COMPUTE = [&](int buf) {
        bf16x8 af[4], bg[4];
        #pragma unroll
        for (int mi=0; mi<4; ++mi)
            af[mi] = *(const bf16x8*)((char*)Al[buf] + (wr*64 + mi*16 + lr)*64 + tsw);
        #pragma unroll
        for (int nj=0; nj<4; ++nj)
            bg[nj] = *(const bf16x8*)((char*)Bl[buf] + (wc*64 + nj*16 + lr)*64 + tsw);
        asm volatile("s_waitcnt lgkmcnt(0)" ::: "memory");
        __builtin_amdgcn_sched_barrier(0);
        #pragma unroll
        for (int mi=0; mi<4; ++mi)
            #pragma unroll
            for (int nj=0; nj<4; ++nj)
                acc[mi][nj] = __builtin_amdgcn_mfma_f32_16x16x32_bf16(
                    af[mi], bg[nj], acc[mi][nj], 0, 0, 0);
    };

    STAGE(0, 0);                       // outstanding: 4
    STAGE(1, 1);                       // outstanding: 8
    int cur = 0;
    for (int kt = 0; kt < 15; ++kt) {
        asm volatile("s_waitcnt vmcnt(4)" ::: "memory");   // tile kt landed
        __builtin_amdgcn_s_barrier();                      // all waves' parts
        __builtin_amdgcn_sched_barrier(0);
        COMPUTE(cur);
        __builtin_amdgcn_s_barrier();                      // reads of cur done
        __builtin_amdgcn_sched_barrier(0);
        if (kt < 14) STAGE(kt+2, cur);                     // refill; out -> 8
        cur ^= 1;
    }
    asm volatile("s_waitcnt vmcnt(0)" ::: "memory");       // final tile
    __builtin_amdgcn_s_barrier();
    __builtin_amdgcn_sched_barrier(0);
    COMPUTE(cur);
}

// ---------------------------------------------------------------------------
// Kernel 3a: batched QKV projection. z=0 -> qhb, z=1 -> khb,
// z=2 -> vhb (row-major) + vhT (per-head transposed, ushort4-packed stores).
// ---------------------------------------------------------------------------
__global__ __launch_bounds__(256, 3)
void gemm_qkv_kernel(const __hip_bfloat16* __restrict__ Abase,
                     const __hip_bfloat16* __restrict__ Wall,
                     __hip_bfloat16* __restrict__ qkout,
                     __hip_bfloat16* __restrict__ vhb,
                     __hip_bfloat16* __restrict__ vhT) {
    __shared__ __hip_bfloat16 Al[2][128*32];
    __shared__ __hip_bfloat16 Bl[2][128*32];
    const int tid = threadIdx.x;
    const int bm = blockIdx.x, bn = blockIdx.y, z = blockIdx.z;
    const size_t MD = (size_t)MROWS*DIM, DD = (size_t)DIM*DIM;
    const __hip_bfloat16* A = Abase + (size_t)z*MD;
    const __hip_bfloat16* W = Wall + (size_t)z*DD;
    f32x4 acc[4][4];
    #pragma unroll
    for (int mi=0; mi<4; ++mi)
        #pragma unroll
        for (int nj=0; nj<4; ++nj) acc[mi][nj] = (f32x4){0.f,0.f,0.f,0.f};
    gemm_core(A, W, Al, Bl, tid, bm, bn, acc);

    const int l = tid&63, lr = l&15, lg = l>>4;
    const int w = tid>>6, wr = w>>1, wc = w&1;
    __hip_bfloat16* dst = (z < 2) ? (qkout + (size_t)z*MD) : vhb;
    #pragma unroll
    for (int mi=0; mi<4; ++mi) {
        #pragma unroll
        for (int nj=0; nj<4; ++nj) {
            const int col = bn*128 + wc*64 + nj*16 + lr;
            const int row0 = bm*128 + wr*64 + mi*16 + lg*4;
            union { ushort4 u; __hip_bfloat16 h[4]; } pk;
            #pragma unroll
            for (int r=0; r<4; ++r) {
                const __hip_bfloat16 bv = __float2bfloat16(acc[mi][nj][r]);
                pk.h[r] = bv;
                dst[(size_t)(row0 + r)*DIM + col] = bv;
            }
            if (z == 2) {
                const int b = row0 >> 9, sp = row0 & 511;
                const int h = col >> 6, d = col & 63;
                *(ushort4*)(vhT + ((size_t)(b*NH + h)*DHEAD + d)*SEQ + sp) = pk.u;
            }
        }
    }
}

// ---------------------------------------------------------------------------
// Kernel 3b: batched FC. z=0: outDyn = dynb @ fc1^T; z=1: outStat = vhb @ fc2^T.
// ---------------------------------------------------------------------------
__global__ __launch_bounds__(256, 3)
void gemm_fc_kernel(const __hip_bfloat16* __restrict__ dynb,
                    const __hip_bfloat16* __restrict__ vhb,
                    const __hip_bfloat16* __restrict__ Wfc,
                    float* __restrict__ outbase) {
    __shared__ __hip_bfloat16 Al[2][128*32];
    __shared__ __hip_bfloat16 Bl[2][128*32];
    const int tid = threadIdx.x;
    const int bm = blockIdx.x, bn = blockIdx.y, z = blockIdx.z;
    const size_t MD = (size_t)MROWS*DIM, DD = (size_t)DIM*DIM;
    const __hip_bfloat16* A = z ? vhb : dynb;
    const __hip_bfloat16* W = Wfc + (size_t)z*DD;
    f32x4 acc[4][4];
    #pragma unroll
    for (int mi=0; mi<4; ++mi)
        #pragma unroll
        for (int nj=0; nj<4; ++nj) acc[mi][nj] = (f32x4){0.f,0.f,0.f,0.f};
    gemm_core(A, W, Al, Bl, tid, bm, bn, acc);

    const int l = tid&63, lr = l&15, lg = l>>4;
    const int w = tid>>6, wr = w>>1, wc = w&1;
    float* dst = outbase + (size_t)z*MD;
    #pragma unroll
    for (int mi=0; mi<4; ++mi)
        #pragma unroll
        for (int nj=0; nj<4; ++nj)
            #pragma unroll
            for (int r=0; r<4; ++r) {
                const int row = bm*128 + wr*64 + mi*16 + lg*4 + r;
                const int col = bn*128 + wc*64 + nj*16 + lr;
                dst[(size_t)row*DIM + col] = acc[mi][nj][r];
            }
}

// ---------------------------------------------------------------------------
// Kernel 4: MFMA attention (validated, unchanged). dynpre out in bf16.
// ---------------------------------------------------------------------------
__global__ __launch_bounds__(256)
void attn_mfma_kernel(const __hip_bfloat16* __restrict__ qhb,
                      const __hip_bfloat16* __restrict__ khb,
                      const __hip_bfloat16* __restrict__ vhT,
                      float* __restrict__ attn_out,
                      __hip_bfloat16* __restrict__ dynb) {
    __shared__ __hip_bfloat16 P_lds[16*512];   // 16KB, XOR-swizzled
    __shared__ float redbuf[2][4][16];
    const int tid = threadIdx.x;
    const int qt = blockIdx.x, h = blockIdx.y, b = blockIdx.z;
    const int q0 = qt * 16;
    const int w  = tid >> 6;
    const int l  = tid & 63;
    const int lr = l & 15;
    const int lg = l >> 4;

    const size_t qoff = (size_t)(b*SEQ + q0 + lr)*DIM + h*DHEAD + lg*8;
    const bf16x8 qf0 = *(const bf16x8*)(qhb + qoff);
    const bf16x8 qf1 = *(const bf16x8*)(qhb + qoff + 32);

    f32x4 acc[8];
    #pragma unroll
    for (int t = 0; t < 8; ++t) acc[t] = (f32x4){0.f, 0.f, 0.f, 0.f};
    #pragma unroll
    for (int t = 0; t < 8; ++t) {
        const int kbase = w*128 + t*16;
        const size_t koff = (size_t)(b*SEQ + kbase + lr)*DIM + h*DHEAD + lg*8;
        const bf16x8 kf0 = *(const bf16x8*)(khb + koff);
        const bf16x8 kf1 = *(const bf16x8*)(khb + koff + 32);
        acc[t] = __builtin_amdgcn_mfma_f32_16x16x32_bf16(qf0, kf0, acc[t], 0, 0, 0);
        acc[t] = __builtin_amdgcn_mfma_f32_16x16x32_bf16(qf1, kf1, acc[t], 0, 0, 0);
    }

    float m[4];
    #pragma unroll
    for (int r = 0; r < 4; ++r) {
        const int grow = q0 + lg*4 + r;
        float mx = -1e30f;
        #pragma unroll
        for (int t = 0; t < 8; ++t) {
            float vv = acc[t][r] * 0.125f;
            if (w*128 + t*16 + lr == grow) vv = -1e30f;
            acc[t][r] = vv;
            mx = fmaxf(mx, vv);
        }
        #pragma unroll
        for (int off = 1; off < 16; off <<= 1) mx = fmaxf(mx, __shfl_xor(mx, off));
        m[r] = mx;
    }
    if (lr == 0) redbuf[0][w][lg*4+0] = m[0];
    if (lr == 1) redbuf[0][w][lg*4+1] = m[1];
    if (lr == 2) redbuf[0][w][lg*4+2] = m[2];
    if (lr == 3) redbuf[0][w][lg*4+3] = m[3];
    __syncthreads();
    float s[4];
    #pragma unroll
    for (int r = 0; r < 4; ++r) {
        const int rr = lg*4 + r;
        const float mx = fmaxf(fmaxf(redbuf[0][0][rr], redbuf[0][1][rr]),
                               fmaxf(redbuf[0][2][rr], redbuf[0][3][rr]));
        float sum = 0.f;
        #pragma unroll
        for (int t = 0; t < 8; ++t) {
            const float e = __expf(acc[t][r] - mx);
            acc[t][r] = e;
            sum += e;
        }
        #pragma unroll
        for (int off = 1; off < 16; off <<= 1) sum += __shfl_xor(sum, off);
        s[r] = sum;
    }
    if (lr == 0) redbuf[1][w][lg*4+0] = s[0];
    if (lr == 1) redbuf[1][w][lg*4+1] = s[1];
    if (lr == 2) redbuf[1][w][lg*4+2] = s[2];
    if (lr == 3) redbuf[1][w][lg*4+3] = s[3];
    __syncthreads();

    float* arow = attn_out + ((size_t)(h*NB + b)*SEQ + q0)*SEQ + w*128;
    #pragma unroll
    for (int r = 0; r < 4; ++r) {
        const int rr = lg*4 + r;
        const float inv = 1.0f / (redbuf[1][0][rr] + redbuf[1][1][rr] +
                                  redbuf[1][2][rr] + redbuf[1][3][rr]);
        #pragma unroll
        for (int t = 0; t < 8; ++t) {
            const float p = acc[t][r] * inv;
            arow[(size_t)rr*SEQ + t*16 + lr] = p;
            const int col = w*128 + t*16 + lr;
            int byte = rr*1024 + col*2;
            byte ^= (rr & 7) << 4;
            *(__hip_bfloat16*)((char*)P_lds + byte) = __float2bfloat16(p);
        }
    }
    __syncthreads();

    f32x4 oa = (f32x4){0.f, 0.f, 0.f, 0.f};
    f32x4 ob = (f32x4){0.f, 0.f, 0.f, 0.f};
    const size_t vbase = ((size_t)(b*NH + h)*DHEAD + w*16 + lr)*SEQ;
    #pragma unroll
    for (int ks = 0; ks < 16; ks += 2) {
        int byte0 = lr*1024 + ks*64 + lg*16;
        byte0 ^= (lr & 7) << 4;
        const bf16x8 pa0 = *(const bf16x8*)((char*)P_lds + byte0);
        const bf16x8 pb0 = *(const bf16x8*)(vhT + vbase + ks*32 + lg*8);
        oa = __builtin_amdgcn_mfma_f32_16x16x32_bf16(pa0, pb0, oa, 0, 0, 0);
        int byte1 = lr*1024 + (ks+1)*64 + lg*16;
        byte1 ^= (lr & 7) << 4;
        const bf16x8 pa1 = *(const bf16x8*)((char*)P_lds + byte1);
        const bf16x8 pb1 = *(const bf16x8*)(vhT + vbase + (ks+1)*32 + lg*8);
        ob = __builtin_amdgcn_mfma_f32_16x16x32_bf16(pa1, pb1, ob, 0, 0, 0);
    }
    #pragma unroll
    for (int r = 0; r < 4; ++r) {
        dynb[(size_t)(b*SEQ + q0 + lg*4 + r)*DIM + h*DHEAD + w*16 + lr]
            = __float2bfloat16(oa[r] + ob[r]);
    }
}

// ---------------------------------------------------------------------------
extern "C" void kernel_launch(void* const* d_in, const int* in_sizes, int n_in,
                              void* d_out, int out_size, void* d_ws, size_t ws_size,
                              hipStream_t stream) {
    const float* q    = (const float*)d_in[0];
    const float* k    = (const float*)d_in[1];
    const float* v    = (const float*)d_in[2];
    const float* Wq   = (const float*)d_in[3];
    const float* Wk   = (const float*)d_in[4];
    const float* Wv   = (const float*)d_in[5];
    const float* fc1  = (const float*)d_in[6];
    const float* fc2  = (const float*)d_in[7];
    const float* ln1g = (const float*)d_in[8];
    const float* ln1b = (const float*)d_in[9];
    const float* ln2g = (const float*)d_in[10];
    const float* ln2b = (const float*)d_in[11];
    const float* ln3g = (const float*)d_in[12];
    const float* ln3b = (const float*)d_in[13];

    const size_t DD = (size_t)DIM*DIM;       // 262144
    const size_t MD = (size_t)MROWS*DIM;     // 4194304
    __hip_bfloat16* Wall = (__hip_bfloat16*)d_ws;       // 5*DD = 2.5MB
    __hip_bfloat16* qnb  = Wall + 5*DD;      // qn,kn,vn contiguous (batched A)
    __hip_bfloat16* knb  = qnb + MD;
    __hip_bfloat16* vnb  = knb + MD;
    __hip_bfloat16* qhb  = vnb + MD;         // qh,kh contiguous
    __hip_bfloat16* khb  = qhb + MD;
    __hip_bfloat16* vhT  = khb + MD;
    __hip_bfloat16* vhb  = vhT + MD;
    __hip_bfloat16* dynb = vhb + MD;         // total ~70MB

    float* outDyn  = (float*)d_out;
    float* outAttn = outDyn + 2*MD;

    ln_fused_kernel<<<dim3(MROWS, 3), 128, 0, stream>>>(
        q, k, v, ln1g, ln1b, ln2g, ln2b, ln3g, ln3b, qnb, knb, vnb);
    wconv_kernel<<<dim3(256, 5), 256, 0, stream>>>(Wq, Wk, Wv, fc1, fc2, Wall);

    gemm_qkv_kernel<<<dim3(MROWS/128, DIM/128, 3), 256, 0, stream>>>(
        qnb, Wall, qhb, vhb, vhT);

    attn_mfma_kernel<<<dim3(SEQ/16, NH, NB), 256, 0, stream>>>(
        qhb, khb, vhT, outAttn, dynb);

    gemm_fc_kernel<<<dim3(MROWS/128, DIM/128, 2), 256, 0, stream>>>(
        dynb, vhb, Wall + 3*DD, outDyn);
}